// Round 1
// baseline (40440.918 us; speedup 1.0000x reference)
//
#include <hip/hip_runtime.h>
#include <stdint.h>

typedef unsigned long long u64;

#define Bq 64
#define Tq 256
#define Hq 512
#define Eq 512
#define Vq 32000

__device__ __forceinline__ float sigmoid_f(float x) { return 1.0f / (1.0f + expf(-x)); }

__device__ __forceinline__ unsigned f2sortable(float f) {
    unsigned u = __float_as_uint(f);
    return (u & 0x80000000u) ? ~u : (u | 0x80000000u);
}

// State layout "stateT": element (k, b) stored at (k>>2)*256 + b*4 + (k&3).
// A float4 load at index kq*64+b yields k = 4*kq..4*kq+3 for batch b (coalesced).

#define DOT4(acc, a, wv) \
    acc = fmaf((a).w, (wv).w, fmaf((a).z, (wv).z, fmaf((a).y, (wv).y, fmaf((a).x, (wv).x, (acc)))))

__global__ __launch_bounds__(256) void lstm_layer_kernel(
    const float* __restrict__ emb,      // embedding (V, E) — layer0 x-part
    const int*   __restrict__ xcol,     // x (B, T); we read x[b*T]
    const u64*   __restrict__ amax_in,  // packed argmax from previous step
    const float* __restrict__ inpT,     // layer1 input = h0T (stateT layout)
    const float* __restrict__ hprevT,   // this layer's h(t-1) (stateT layout)
    float*       __restrict__ houtT,    // this layer's h(t) (stateT layout)
    float*       __restrict__ cstate,   // [H][B]
    const float* __restrict__ Wih,      // (4H, 512) pre-offset for layer
    const float* __restrict__ Whh,      // (4H, 512) pre-offset for layer
    const float* __restrict__ bih,      // (4H) pre-offset
    const float* __restrict__ bhh,      // (4H) pre-offset
    u64*         __restrict__ amax_reset, // non-null: reset argmax buf (layer1)
    int t, int is_layer0)
{
    const int h    = blockIdx.x;              // one hidden unit per block
    const int tid  = threadIdx.x;
    const int wave = __builtin_amdgcn_readfirstlane(tid >> 6);
    const int lane = tid & 63;                // batch index

    // Reset argmax accumulator for this step (runs in layer1, i.e. after
    // layer0 consumed last step's argmax and before FC atomics).
    if (amax_reset && blockIdx.x == 0 && wave == 3) amax_reset[lane] = 0;

    const int part = wave >> 1;               // 0: input-part, 1: hidden-part
    const int kq0  = (wave & 1) << 6;         // float4-index base: 0 or 64

    const float4* W4 = (const float4*)(part ? Whh : Wih);
    const int r0 = (0 * Hq + h) * 128;        // gate i row
    const int r1 = (1 * Hq + h) * 128;        // gate f row
    const int r2 = (2 * Hq + h) * 128;        // gate g row
    const int r3 = (3 * Hq + h) * 128;        // gate o row

    float acc0 = 0.f, acc1 = 0.f, acc2 = 0.f, acc3 = 0.f;

    if (part == 0 && is_layer0) {
        // x-part of layer0: gather embedding row directly (L1-friendly)
        int row = (t == 0) ? xcol[lane * Tq] : (int)(~(unsigned)amax_in[lane]);
        const float4* a4 = (const float4*)(emb + (size_t)row * Eq) + kq0;
        #pragma unroll 4
        for (int i = 0; i < 64; ++i) {
            float4 a = a4[i];
            int kq = kq0 + i;
            float4 w0 = W4[r0 + kq], w1 = W4[r1 + kq];
            float4 w2 = W4[r2 + kq], w3 = W4[r3 + kq];
            DOT4(acc0, a, w0); DOT4(acc1, a, w1);
            DOT4(acc2, a, w2); DOT4(acc3, a, w3);
        }
    } else {
        const float4* a4 = (const float4*)(part ? hprevT : inpT);
        #pragma unroll 4
        for (int i = 0; i < 64; ++i) {
            int kq = kq0 + i;
            float4 a = a4[kq * 64 + lane];
            float4 w0 = W4[r0 + kq], w1 = W4[r1 + kq];
            float4 w2 = W4[r2 + kq], w3 = W4[r3 + kq];
            DOT4(acc0, a, w0); DOT4(acc1, a, w1);
            DOT4(acc2, a, w2); DOT4(acc3, a, w3);
        }
    }

    __shared__ float red[4][4][64];
    red[wave][0][lane] = acc0;
    red[wave][1][lane] = acc1;
    red[wave][2][lane] = acc2;
    red[wave][3][lane] = acc3;
    __syncthreads();

    if (wave == 0) {
        float gi = red[0][0][lane] + red[1][0][lane] + red[2][0][lane] + red[3][0][lane]
                 + bih[0 * Hq + h] + bhh[0 * Hq + h];
        float gf = red[0][1][lane] + red[1][1][lane] + red[2][1][lane] + red[3][1][lane]
                 + bih[1 * Hq + h] + bhh[1 * Hq + h];
        float gg = red[0][2][lane] + red[1][2][lane] + red[2][2][lane] + red[3][2][lane]
                 + bih[2 * Hq + h] + bhh[2 * Hq + h];
        float go = red[0][3][lane] + red[1][3][lane] + red[2][3][lane] + red[3][3][lane]
                 + bih[3 * Hq + h] + bhh[3 * Hq + h];
        float cold = cstate[h * 64 + lane];
        float cn = sigmoid_f(gf) * cold + sigmoid_f(gi) * tanhf(gg);
        float hn = sigmoid_f(go) * tanhf(cn);
        cstate[h * 64 + lane] = cn;
        houtT[(h >> 2) * 256 + lane * 4 + (h & 3)] = hn;
    }
}

__global__ __launch_bounds__(256) void fc_kernel(
    const float* __restrict__ hT,       // h1T (stateT layout)
    const float* __restrict__ Wfc,      // (V, H)
    const float* __restrict__ bfc,      // (V)
    float*       __restrict__ out,      // (B, V), written only on last step
    u64*         __restrict__ amax,     // packed argmax accumulator
    int write_out)
{
    const int tid  = threadIdx.x;
    const int wave = tid >> 6;
    const int lane = tid & 63;          // batch index
    const int w    = __builtin_amdgcn_readfirstlane(blockIdx.x * 4 + wave);
    const int v0   = w * 8;             // 8 vocab columns per wave

    const float4* A4 = (const float4*)hT;
    const float4* W4 = (const float4*)Wfc;

    float acc[8];
    #pragma unroll
    for (int j = 0; j < 8; ++j) acc[j] = 0.f;

    #pragma unroll 2
    for (int kq = 0; kq < 128; ++kq) {
        float4 a = A4[kq * 64 + lane];
        #pragma unroll
        for (int j = 0; j < 8; ++j) {
            float4 wv = W4[(size_t)(v0 + j) * 128 + kq];
            DOT4(acc[j], a, wv);
        }
    }

    float best = -__builtin_huge_valf();
    int bi = 0;
    #pragma unroll
    for (int j = 0; j < 8; ++j) {
        float lg = acc[j] + bfc[v0 + j];
        acc[j] = lg;
        if (lg > best) { best = lg; bi = v0 + j; }   // '>' keeps smallest idx on tie
    }
    u64 pack = ((u64)f2sortable(best) << 32) | (u64)(~(unsigned)bi);

    __shared__ u64 redm[4][64];
    redm[wave][lane] = pack;
    __syncthreads();
    if (wave == 0) {
        u64 m = redm[0][lane];
        u64 m1 = redm[1][lane]; if (m1 > m) m = m1;
        u64 m2 = redm[2][lane]; if (m2 > m) m = m2;
        u64 m3 = redm[3][lane]; if (m3 > m) m = m3;
        atomicMax(&amax[lane], m);
    }

    if (write_out) {
        float4* o4 = (float4*)(out + (size_t)lane * Vq + v0);
        o4[0] = make_float4(acc[0], acc[1], acc[2], acc[3]);
        o4[1] = make_float4(acc[4], acc[5], acc[6], acc[7]);
    }
}

extern "C" void kernel_launch(void* const* d_in, const int* in_sizes, int n_in,
                              void* d_out, int out_size, void* d_ws, size_t ws_size,
                              hipStream_t stream)
{
    const int*   x   = (const int*)d_in[0];
    const float* emb = (const float*)d_in[1];
    const float* Wih = (const float*)d_in[2];
    const float* Whh = (const float*)d_in[3];
    const float* bih = (const float*)d_in[4];
    const float* bhh = (const float*)d_in[5];
    const float* Wfc = (const float*)d_in[6];
    const float* bfc = (const float*)d_in[7];
    float* out = (float*)d_out;

    float* ws = (float*)d_ws;
    float* h0T[2] = { ws,          ws + 32768 };
    float* h1T[2] = { ws + 65536,  ws + 98304 };
    float* c0 = ws + 131072;
    float* c1 = ws + 163840;
    u64* amax = (u64*)(ws + 196608);

    // zero h/c state (and amax slot, harmless)
    hipMemsetAsync(d_ws, 0, 196608 * sizeof(float) + 64 * sizeof(u64), stream);

    const size_t WL = (size_t)4 * Hq * 512;   // per-layer weight stride (4H x 512)
    for (int t = 0; t < Tq; ++t) {
        int rd = t & 1, wr = (t + 1) & 1;
        // layer 0: input = embedding gather
        lstm_layer_kernel<<<512, 256, 0, stream>>>(
            emb, x, amax, nullptr, h0T[rd], h0T[wr], c0,
            Wih, Whh, bih, bhh,
            nullptr, t, 1);
        // layer 1: input = h0(t); also resets argmax accumulator for this step
        lstm_layer_kernel<<<512, 256, 0, stream>>>(
            emb, x, amax, h0T[wr], h1T[rd], h1T[wr], c1,
            Wih + WL, Whh + WL, bih + 4 * Hq, bhh + 4 * Hq,
            amax, t, 0);
        // FC head + argmax (+ logits store on final step)
        fc_kernel<<<1000, 256, 0, stream>>>(
            h1T[wr], Wfc, bfc, out, amax, (t == Tq - 1) ? 1 : 0);
    }
}

// Round 2
// 35284.900 us; speedup vs baseline: 1.1461x; 1.1461x over previous
//
#include <hip/hip_runtime.h>
#include <stdint.h>

typedef unsigned long long u64;

#define Bq 64
#define Tq 256
#define Hq 512
#define Eq 512
#define Vq 32000

__device__ __forceinline__ float sigmoid_f(float x) { return 1.0f / (1.0f + expf(-x)); }

__device__ __forceinline__ unsigned f2sortable(float f) {
    unsigned u = __float_as_uint(f);
    return (u & 0x80000000u) ? ~u : (u | 0x80000000u);
}

// State layout "stateT": element (k, b) stored at (k>>2)*256 + b*4 + (k&3).
// A float4 load at index kq*64+b yields k = 4*kq..4*kq+3 for batch b (coalesced).

#define DOT4(acc, a, wv) \
    acc = fmaf((a).w, (wv).w, fmaf((a).z, (wv).z, fmaf((a).y, (wv).y, fmaf((a).x, (wv).x, (acc)))))

// ---------------------------------------------------------------------------
// LSTM layer kernel: one block per hidden unit h. 4 waves: (part, k-half).
// Weights for this unit's 8 rows (4 gates x {ih,hh}) are cooperatively staged
// into LDS with coalesced 1KB/instr loads, then consumed as LDS broadcasts.
// ---------------------------------------------------------------------------
__global__ __launch_bounds__(256) void lstm_layer_kernel(
    const float* __restrict__ emb,      // embedding (V, E) — layer0 x-part
    const int*   __restrict__ xcol,     // x (B, T); we read x[b*T]
    const u64*   __restrict__ amax_in,  // packed argmax from previous step
    const float* __restrict__ inpT,     // layer1 input = h0T (stateT layout)
    const float* __restrict__ hprevT,   // this layer's h(t-1) (stateT layout)
    float*       __restrict__ houtT,    // this layer's h(t) (stateT layout)
    float*       __restrict__ cstate,   // [H][B]
    const float* __restrict__ Wih,      // (4H, 512) pre-offset for layer
    const float* __restrict__ Whh,      // (4H, 512) pre-offset for layer
    const float* __restrict__ bih,      // (4H) pre-offset
    const float* __restrict__ bhh,      // (4H) pre-offset
    u64*         __restrict__ amax_reset, // non-null: reset argmax buf (layer1)
    int t, int is_layer0)
{
    __shared__ float4 wlds[1024];             // 8 rows x 128 f4 = 16KB
    const int h    = blockIdx.x;              // hidden unit
    const int tid  = threadIdx.x;
    const int wave = __builtin_amdgcn_readfirstlane(tid >> 6);
    const int lane = tid & 63;                // batch index

    if (amax_reset && blockIdx.x == 0 && wave == 3) amax_reset[lane] = 0;

    // --- cooperative weight staging: seg s in 0..7 -> (part=s>>2, gate=s&3)
    const float4* Wih4 = (const float4*)Wih;
    const float4* Whh4 = (const float4*)Whh;
    #pragma unroll
    for (int i = 0; i < 4; ++i) {
        int g   = i * 256 + tid;              // 0..1023
        int s   = g >> 7;                     // segment (wave-uniform per i)
        int off = g & 127;
        const float4* src = (s < 4) ? Wih4 : Whh4;
        wlds[g] = src[(size_t)((s & 3) * Hq + h) * 128 + off];
    }
    __syncthreads();

    const int part = wave >> 1;               // 0: input-part, 1: hidden-part
    const int q    = wave & 1;                // k-half
    const int kq0  = q << 6;                  // f4 base: 0 or 64

    float acc0 = 0.f, acc1 = 0.f, acc2 = 0.f, acc3 = 0.f;

    if (part == 0 && is_layer0) {
        int row = (t == 0) ? xcol[lane * Tq] : (int)(~(unsigned)amax_in[lane]);
        const float4* a4 = (const float4*)(emb + (size_t)row * Eq);
        #pragma unroll 4
        for (int i = 0; i < 64; ++i) {
            float4 a = a4[kq0 + i];
            int kq = kq0 + i;
            float4 w0 = wlds[(0 * 4 + 0) * 128 + kq];
            float4 w1 = wlds[(0 * 4 + 1) * 128 + kq];
            float4 w2 = wlds[(0 * 4 + 2) * 128 + kq];
            float4 w3 = wlds[(0 * 4 + 3) * 128 + kq];
            DOT4(acc0, a, w0); DOT4(acc1, a, w1);
            DOT4(acc2, a, w2); DOT4(acc3, a, w3);
        }
    } else {
        const float4* a4 = (const float4*)(part ? hprevT : inpT);
        #pragma unroll 4
        for (int i = 0; i < 64; ++i) {
            int kq = kq0 + i;
            float4 a = a4[kq * 64 + lane];
            float4 w0 = wlds[(part * 4 + 0) * 128 + kq];
            float4 w1 = wlds[(part * 4 + 1) * 128 + kq];
            float4 w2 = wlds[(part * 4 + 2) * 128 + kq];
            float4 w3 = wlds[(part * 4 + 3) * 128 + kq];
            DOT4(acc0, a, w0); DOT4(acc1, a, w1);
            DOT4(acc2, a, w2); DOT4(acc3, a, w3);
        }
    }

    __shared__ float red[4][4][64];
    red[wave][0][lane] = acc0;
    red[wave][1][lane] = acc1;
    red[wave][2][lane] = acc2;
    red[wave][3][lane] = acc3;
    __syncthreads();

    if (wave == 0) {
        float gi = red[0][0][lane] + red[1][0][lane] + red[2][0][lane] + red[3][0][lane]
                 + bih[0 * Hq + h] + bhh[0 * Hq + h];
        float gf = red[0][1][lane] + red[1][1][lane] + red[2][1][lane] + red[3][1][lane]
                 + bih[1 * Hq + h] + bhh[1 * Hq + h];
        float gg = red[0][2][lane] + red[1][2][lane] + red[2][2][lane] + red[3][2][lane]
                 + bih[2 * Hq + h] + bhh[2 * Hq + h];
        float go = red[0][3][lane] + red[1][3][lane] + red[2][3][lane] + red[3][3][lane]
                 + bih[3 * Hq + h] + bhh[3 * Hq + h];
        float cold = cstate[h * 64 + lane];
        float cn = sigmoid_f(gf) * cold + sigmoid_f(gi) * tanhf(gg);
        float hn = sigmoid_f(go) * tanhf(cn);
        cstate[h * 64 + lane] = cn;
        houtT[(h >> 2) * 256 + lane * 4 + (h & 3)] = hn;
    }
}

// ---------------------------------------------------------------------------
// FC head: block = 64 vocab rows x all 64 batches. K chunked by 128; each
// chunk's 64x128 weight tile (32KB) staged into LDS with coalesced loads.
// Wave w computes rows w*16..w*16+15 (acc[16]/lane), lane = batch.
// ---------------------------------------------------------------------------
__global__ __launch_bounds__(256) void fc_kernel(
    const float* __restrict__ hT,       // h1T (stateT layout)
    const float* __restrict__ Wfc,      // (V, H)
    const float* __restrict__ bfc,      // (V)
    float*       __restrict__ out,      // (B, V), written only on last step
    u64*         __restrict__ amax,     // packed argmax accumulator
    int write_out)
{
    __shared__ float4 wlds[2048];       // 64 rows x 32 f4 = 32KB
    const int tid  = threadIdx.x;
    const int wave = __builtin_amdgcn_readfirstlane(tid >> 6);
    const int lane = tid & 63;          // batch index
    const int v0   = blockIdx.x * 64;   // block's vocab base
    const int r0   = wave * 16;         // wave's row base within block

    const float4* A4 = (const float4*)hT;
    const float4* W4 = (const float4*)Wfc;

    float acc[16];
    #pragma unroll
    for (int j = 0; j < 16; ++j) acc[j] = 0.f;

    for (int c = 0; c < 4; ++c) {
        __syncthreads();                // protect LDS tile reuse
        // coop load: 64 rows x 32 f4 (K chunk c). g = tid + i*256:
        // row = g>>5, off = g&31 — 32 consecutive lanes load 512B contiguous.
        #pragma unroll
        for (int i = 0; i < 8; ++i) {
            int g = tid + i * 256;
            int r = g >> 5, off = g & 31;
            wlds[g] = W4[(size_t)(v0 + r) * 128 + c * 32 + off];
        }
        __syncthreads();
        #pragma unroll 4
        for (int kq = 0; kq < 32; ++kq) {
            float4 a = A4[(c * 32 + kq) * 64 + lane];
            #pragma unroll
            for (int j = 0; j < 16; ++j) {
                float4 wv = wlds[(r0 + j) * 32 + kq];
                DOT4(acc[j], a, wv);
            }
        }
    }

    float best = -__builtin_huge_valf();
    int bi = 0;
    #pragma unroll
    for (int j = 0; j < 16; ++j) {
        float lg = acc[j] + bfc[v0 + r0 + j];
        acc[j] = lg;
        if (lg > best) { best = lg; bi = v0 + r0 + j; }  // '>' keeps smallest idx
    }
    u64 pack = ((u64)f2sortable(best) << 32) | (u64)(~(unsigned)bi);

    __shared__ u64 redm[4][64];
    redm[wave][lane] = pack;
    __syncthreads();
    if (wave == 0) {
        u64 m = redm[0][lane];
        u64 m1 = redm[1][lane]; if (m1 > m) m = m1;
        u64 m2 = redm[2][lane]; if (m2 > m) m = m2;
        u64 m3 = redm[3][lane]; if (m3 > m) m = m3;
        atomicMax(&amax[lane], m);
    }

    if (write_out) {
        #pragma unroll
        for (int j = 0; j < 16; ++j)
            out[(size_t)lane * Vq + v0 + r0 + j] = acc[j];
    }
}

extern "C" void kernel_launch(void* const* d_in, const int* in_sizes, int n_in,
                              void* d_out, int out_size, void* d_ws, size_t ws_size,
                              hipStream_t stream)
{
    const int*   x   = (const int*)d_in[0];
    const float* emb = (const float*)d_in[1];
    const float* Wih = (const float*)d_in[2];
    const float* Whh = (const float*)d_in[3];
    const float* bih = (const float*)d_in[4];
    const float* bhh = (const float*)d_in[5];
    const float* Wfc = (const float*)d_in[6];
    const float* bfc = (const float*)d_in[7];
    float* out = (float*)d_out;

    float* ws = (float*)d_ws;
    float* h0T[2] = { ws,          ws + 32768 };
    float* h1T[2] = { ws + 65536,  ws + 98304 };
    float* c0 = ws + 131072;
    float* c1 = ws + 163840;
    u64* amax = (u64*)(ws + 196608);

    hipMemsetAsync(d_ws, 0, 196608 * sizeof(float) + 64 * sizeof(u64), stream);

    const size_t WL = (size_t)4 * Hq * 512;   // per-layer weight stride
    for (int t = 0; t < Tq; ++t) {
        int rd = t & 1, wr = (t + 1) & 1;
        lstm_layer_kernel<<<512, 256, 0, stream>>>(
            emb, x, amax, nullptr, h0T[rd], h0T[wr], c0,
            Wih, Whh, bih, bhh,
            nullptr, t, 1);
        lstm_layer_kernel<<<512, 256, 0, stream>>>(
            emb, x, amax, h0T[wr], h1T[rd], h1T[wr], c1,
            Wih + WL, Whh + WL, bih + 4 * Hq, bhh + 4 * Hq,
            amax, t, 0);
        fc_kernel<<<500, 256, 0, stream>>>(
            h1T[wr], Wfc, bfc, out, amax, (t == Tq - 1) ? 1 : 0);
    }
}

// Round 3
// 21192.805 us; speedup vs baseline: 1.9082x; 1.6649x over previous
//
#include <hip/hip_runtime.h>
#include <stdint.h>

typedef unsigned long long u64;

#define Bq 64
#define Tq 256
#define Hq 512
#define Eq 512
#define Vq 32000

__device__ __forceinline__ float sigmoid_f(float x) { return 1.0f / (1.0f + expf(-x)); }

__device__ __forceinline__ unsigned f2sortable(float f) {
    unsigned u = __float_as_uint(f);
    return (u & 0x80000000u) ? ~u : (u | 0x80000000u);
}

// async global->LDS, 16B per lane; LDS dest is wave-uniform base + lane*16
__device__ __forceinline__ void gl_lds16(const float* g, float* l) {
    __builtin_amdgcn_global_load_lds(
        (const __attribute__((address_space(1))) void*)g,
        (__attribute__((address_space(3))) void*)l, 16, 0, 0);
}

// State layout "stateT": element (k, b) stored at (k>>2)*256 + b*4 + (k&3).
// float4 at word (kq*256 + b*4) == h[b][4kq..4kq+3]  (per-(b,kq) contiguous).

#define DOT4(acc, a, wv) \
    acc = fmaf((a).w, (wv).w, fmaf((a).z, (wv).z, fmaf((a).y, (wv).y, fmaf((a).x, (wv).x, (acc)))))

// ---------------------------------------------------------------------------
// LSTM layer kernel (unchanged from round 2): one block per hidden unit.
// ---------------------------------------------------------------------------
__global__ __launch_bounds__(256) void lstm_layer_kernel(
    const float* __restrict__ emb,
    const int*   __restrict__ xcol,
    const u64*   __restrict__ amax_in,
    const float* __restrict__ inpT,
    const float* __restrict__ hprevT,
    float*       __restrict__ houtT,
    float*       __restrict__ cstate,
    const float* __restrict__ Wih,
    const float* __restrict__ Whh,
    const float* __restrict__ bih,
    const float* __restrict__ bhh,
    u64*         __restrict__ amax_reset,
    int t, int is_layer0)
{
    __shared__ float4 wlds[1024];             // 8 rows x 128 f4 = 16KB
    const int h    = blockIdx.x;
    const int tid  = threadIdx.x;
    const int wave = __builtin_amdgcn_readfirstlane(tid >> 6);
    const int lane = tid & 63;

    if (amax_reset && blockIdx.x == 0 && wave == 3) amax_reset[lane] = 0;

    const float4* Wih4 = (const float4*)Wih;
    const float4* Whh4 = (const float4*)Whh;
    #pragma unroll
    for (int i = 0; i < 4; ++i) {
        int g   = i * 256 + tid;
        int s   = g >> 7;
        int off = g & 127;
        const float4* src = (s < 4) ? Wih4 : Whh4;
        wlds[g] = src[(size_t)((s & 3) * Hq + h) * 128 + off];
    }
    __syncthreads();

    const int part = wave >> 1;
    const int kq0  = (wave & 1) << 6;

    float acc0 = 0.f, acc1 = 0.f, acc2 = 0.f, acc3 = 0.f;

    if (part == 0 && is_layer0) {
        int row = (t == 0) ? xcol[lane * Tq] : (int)(~(unsigned)amax_in[lane]);
        const float4* a4 = (const float4*)(emb + (size_t)row * Eq);
        #pragma unroll 4
        for (int i = 0; i < 64; ++i) {
            float4 a = a4[kq0 + i];
            int kq = kq0 + i;
            float4 w0 = wlds[0 * 128 + kq];
            float4 w1 = wlds[1 * 128 + kq];
            float4 w2 = wlds[2 * 128 + kq];
            float4 w3 = wlds[3 * 128 + kq];
            DOT4(acc0, a, w0); DOT4(acc1, a, w1);
            DOT4(acc2, a, w2); DOT4(acc3, a, w3);
        }
    } else {
        const float4* a4 = (const float4*)(part ? hprevT : inpT);
        #pragma unroll 4
        for (int i = 0; i < 64; ++i) {
            int kq = kq0 + i;
            float4 a = a4[kq * 64 + lane];
            float4 w0 = wlds[(part * 4 + 0) * 128 + kq];
            float4 w1 = wlds[(part * 4 + 1) * 128 + kq];
            float4 w2 = wlds[(part * 4 + 2) * 128 + kq];
            float4 w3 = wlds[(part * 4 + 3) * 128 + kq];
            DOT4(acc0, a, w0); DOT4(acc1, a, w1);
            DOT4(acc2, a, w2); DOT4(acc3, a, w3);
        }
    }

    __shared__ float red[4][4][64];
    red[wave][0][lane] = acc0;
    red[wave][1][lane] = acc1;
    red[wave][2][lane] = acc2;
    red[wave][3][lane] = acc3;
    __syncthreads();

    if (wave == 0) {
        float gi = red[0][0][lane] + red[1][0][lane] + red[2][0][lane] + red[3][0][lane]
                 + bih[0 * Hq + h] + bhh[0 * Hq + h];
        float gf = red[0][1][lane] + red[1][1][lane] + red[2][1][lane] + red[3][1][lane]
                 + bih[1 * Hq + h] + bhh[1 * Hq + h];
        float gg = red[0][2][lane] + red[1][2][lane] + red[2][2][lane] + red[3][2][lane]
                 + bih[2 * Hq + h] + bhh[2 * Hq + h];
        float go = red[0][3][lane] + red[1][3][lane] + red[2][3][lane] + red[3][3][lane]
                 + bih[3 * Hq + h] + bhh[3 * Hq + h];
        float cold = cstate[h * 64 + lane];
        float cn = sigmoid_f(gf) * cold + sigmoid_f(gi) * tanhf(gg);
        float hn = sigmoid_f(go) * tanhf(cn);
        cstate[h * 64 + lane] = cn;
        houtT[(h >> 2) * 256 + lane * 4 + (h & 3)] = hn;
    }
}

// ---------------------------------------------------------------------------
// FC head, register-blocked 8x8 outer product.
// Block: 64 vocab rows x 64 batches, K=512 split 4-way across waves (128 each),
// K chunked by 64, double-buffered global_load_lds staging with XOR bank
// swizzle (slot s stored at s^group so 8-way broadcast reads span 32 banks).
// lane = rgrp(8 rows-of-8) x bgrp(8 batches-of-8); 64 fp32 accumulators.
// ---------------------------------------------------------------------------
__global__ __launch_bounds__(256) void fc_kernel(
    const float* __restrict__ hT,       // h1 state, stateT layout
    const float* __restrict__ Wfc,      // (V, 512)
    const float* __restrict__ bfc,      // (V)
    float*       __restrict__ out,      // (B, V), written on last step only
    u64*         __restrict__ amax,     // packed argmax accumulator
    int write_out)
{
    __shared__ float lds[2][8192];      // [buf][ W 4096 | A 4096 ] words, 64KB
    const int tid  = threadIdx.x;
    const int wave = __builtin_amdgcn_readfirstlane(tid >> 6);
    const int lane = tid & 63;
    const int rgrp = lane >> 3;         // row group (8 rows each)
    const int bgrp = lane & 7;          // batch group (8 batches each)
    const int v0   = blockIdx.x * 64;

    float acc[8][8];
    #pragma unroll
    for (int j = 0; j < 8; ++j)
        #pragma unroll
        for (int i = 0; i < 8; ++i) acc[j][i] = 0.f;

#define STAGE_CHUNK(cc, dst)                                                  \
    {                                                                         \
        const int k0_ = (cc) * 64;                                            \
        _Pragma("unroll")                                                     \
        for (int it = 0; it < 4; ++it) {                                      \
            int g = it * 256 + tid;                                           \
            int r = g >> 4, sp = g & 15;                                      \
            int gk = k0_ + (((sp ^ (r >> 3)) & 15) << 2);                     \
            gl_lds16(Wfc + (size_t)(v0 + r) * 512 + gk,                       \
                     (dst) + it * 1024 + wave * 256);                         \
        }                                                                     \
        _Pragma("unroll")                                                     \
        for (int it = 0; it < 4; ++it) {                                      \
            int g = it * 256 + tid;                                           \
            int kqr = g >> 6, u = g & 63;                                     \
            int b = (u & 56) | ((u & 7) ^ (u >> 3));                          \
            gl_lds16(hT + (size_t)((cc) * 16 + kqr) * 256 + b * 4,            \
                     (dst) + 4096 + it * 1024 + wave * 256);                  \
        }                                                                     \
    }

    float* cur = lds[0];
    float* nxt = lds[1];

    STAGE_CHUNK(0, cur)
    __syncthreads();                    // drains the DMA before first compute

    for (int c = 0; c < 8; ++c) {
        if (c < 7) STAGE_CHUNK(c + 1, nxt)

        #pragma unroll
        for (int kq = 0; kq < 4; ++kq) {
            const int sl = wave * 4 + kq;       // logical k-slot 0..15 in chunk
            float4 wv[8], av[8];
            #pragma unroll
            for (int j = 0; j < 8; ++j)
                wv[j] = *(const float4*)(cur + (rgrp * 8 + j) * 64 + (((sl ^ rgrp) & 15) << 2));
            #pragma unroll
            for (int i = 0; i < 8; ++i)
                av[i] = *(const float4*)(cur + 4096 + sl * 256 + ((bgrp * 8 + (i ^ bgrp)) << 2));
            #pragma unroll
            for (int j = 0; j < 8; ++j)
                #pragma unroll
                for (int i = 0; i < 8; ++i)
                    DOT4(acc[j][i], av[i], wv[j]);
        }

        __syncthreads();                // barrier drain completes nxt's DMA too
        float* tmp = cur; cur = nxt; nxt = tmp;
    }

    // ---- cross-wave K reduction into accbuf = lds[0] (64x64 fp32) ----
    float* accbuf = lds[0];
    for (int w = 0; w < 4; ++w) {
        if (wave == w) {
            #pragma unroll
            for (int j = 0; j < 8; ++j) {
                float* p = accbuf + (rgrp * 8 + j) * 64 + bgrp * 8;
                if (w == 0) {
                    *(float4*)p       = make_float4(acc[j][0], acc[j][1], acc[j][2], acc[j][3]);
                    *(float4*)(p + 4) = make_float4(acc[j][4], acc[j][5], acc[j][6], acc[j][7]);
                } else {
                    float4 a0 = *(const float4*)p;
                    float4 a1 = *(const float4*)(p + 4);
                    a0.x += acc[j][0]; a0.y += acc[j][1]; a0.z += acc[j][2]; a0.w += acc[j][3];
                    a1.x += acc[j][4]; a1.y += acc[j][5]; a1.z += acc[j][6]; a1.w += acc[j][7];
                    *(float4*)p       = a0;
                    *(float4*)(p + 4) = a1;
                }
            }
        }
        __syncthreads();
    }

    // ---- bias + per-batch argmax + (last step) logit store ----
    const int b  = tid & 63;
    const int rq = wave;                // row quarter: 16 rows each
    float best = -__builtin_huge_valf();
    int bi = 0;
    float lg[16];
    #pragma unroll
    for (int n = 0; n < 16; ++n) {
        int r = rq * 16 + n;
        float v = accbuf[r * 64 + b] + bfc[v0 + r];
        lg[n] = v;
        if (v > best) { best = v; bi = v0 + r; }   // '>' keeps smallest index
    }
    u64 pack = ((u64)f2sortable(best) << 32) | (u64)(~(unsigned)bi);

    u64* redm = (u64*)lds[1];
    redm[rq * 64 + b] = pack;
    __syncthreads();
    if (rq == 0) {
        u64 m  = redm[b];
        u64 m1 = redm[64 + b];  if (m1 > m) m = m1;
        u64 m2 = redm[128 + b]; if (m2 > m) m = m2;
        u64 m3 = redm[192 + b]; if (m3 > m) m = m3;
        atomicMax(&amax[b], m);
    }

    if (write_out) {
        #pragma unroll
        for (int n = 0; n < 16; ++n)
            out[(size_t)b * Vq + v0 + rq * 16 + n] = lg[n];
    }
}

extern "C" void kernel_launch(void* const* d_in, const int* in_sizes, int n_in,
                              void* d_out, int out_size, void* d_ws, size_t ws_size,
                              hipStream_t stream)
{
    const int*   x   = (const int*)d_in[0];
    const float* emb = (const float*)d_in[1];
    const float* Wih = (const float*)d_in[2];
    const float* Whh = (const float*)d_in[3];
    const float* bih = (const float*)d_in[4];
    const float* bhh = (const float*)d_in[5];
    const float* Wfc = (const float*)d_in[6];
    const float* bfc = (const float*)d_in[7];
    float* out = (float*)d_out;

    float* ws = (float*)d_ws;
    float* h0T[2] = { ws,          ws + 32768 };
    float* h1T[2] = { ws + 65536,  ws + 98304 };
    float* c0 = ws + 131072;
    float* c1 = ws + 163840;
    u64* amax = (u64*)(ws + 196608);

    hipMemsetAsync(d_ws, 0, 196608 * sizeof(float) + 64 * sizeof(u64), stream);

    const size_t WL = (size_t)4 * Hq * 512;
    for (int t = 0; t < Tq; ++t) {
        int rd = t & 1, wr = (t + 1) & 1;
        lstm_layer_kernel<<<512, 256, 0, stream>>>(
            emb, x, amax, nullptr, h0T[rd], h0T[wr], c0,
            Wih, Whh, bih, bhh,
            nullptr, t, 1);
        lstm_layer_kernel<<<512, 256, 0, stream>>>(
            emb, x, amax, h0T[wr], h1T[rd], h1T[wr], c1,
            Wih + WL, Whh + WL, bih + 4 * Hq, bhh + 4 * Hq,
            amax, t, 0);
        fc_kernel<<<500, 256, 0, stream>>>(
            h1T[wr], Wfc, bfc, out, amax, (t == Tq - 1) ? 1 : 0);
    }
}